// Round 10
// baseline (425.202 us; speedup 1.0000x reference)
//
#include <hip/hip_runtime.h>
#include <math.h>

#define Bn 8
#define Nn 1024
#define Cn 1024
#define Hn 16
#define Dn 64
#define HIDn 4096
#define SCALEf 0.125f

typedef __bf16 bf16x8 __attribute__((ext_vector_type(8)));
typedef float f32x4 __attribute__((ext_vector_type(4)));

__device__ inline unsigned short f2bf(float f) {
    union { float f; unsigned int u; } v; v.f = f;
    unsigned int r = v.u + 0x7fffu + ((v.u >> 16) & 1u);
    return (unsigned short)(r >> 16);
}

// exact-GELU via inlined Abramowitz-Stegun erf (|err|<=1.5e-7). No libm call.
__device__ inline float gelu_exact(float x) {
    const float z = x * 0.70710678118654752f;
    const float az = fabsf(z);
    const float t = 1.0f / (1.0f + 0.3275911f * az);
    float poly = 0.254829592f +
                 t * (-0.284496736f +
                      t * (1.421413741f + t * (-1.453152027f + t * 1.061405429f)));
    poly *= t;
    const float e = __expf(-az * az);
    float erfv = 1.0f - poly * e;
    erfv = (z < 0.0f) ? -erfv : erfv;
    return 0.5f * x * (1.0f + erfv);
}

__device__ inline void gload_lds16(const void* g, void* l) {
    auto gp = reinterpret_cast<const unsigned int __attribute__((address_space(1)))*>(
        reinterpret_cast<uintptr_t>(g));
    auto lp = reinterpret_cast<unsigned int __attribute__((address_space(3)))*>(
        reinterpret_cast<uintptr_t>(l));
    __builtin_amdgcn_global_load_lds(gp, lp, 16, 0, 0);
}

#define VMC(n)                                           \
    asm volatile("s_waitcnt vmcnt(" #n ")" ::: "memory");\
    __builtin_amdgcn_sched_barrier(0)
#define LGKM0v                                           \
    asm volatile("s_waitcnt lgkmcnt(0)" ::: "memory");   \
    __builtin_amdgcn_sched_barrier(0)

// ---------------- f32 -> bf16 conversion ----------------
__global__ __launch_bounds__(256) void cvt_bf16(const float* __restrict__ in,
                                                unsigned short* __restrict__ out, int n4) {
    int i = blockIdx.x * 256 + threadIdx.x;
    if (i < n4) {
        float4 v = ((const float4*)in)[i];
        ushort4 o;
        o.x = f2bf(v.x); o.y = f2bf(v.y); o.z = f2bf(v.z); o.w = f2bf(v.w);
        ((ushort4*)out)[i] = o;
    }
}

// ---------------- LayerNorm (C=1024), fp32 in -> bf16 out ----------------
__global__ __launch_bounds__(256) void ln_kernel(const float* __restrict__ x,
                                                 const float* __restrict__ g,
                                                 const float* __restrict__ bb,
                                                 unsigned short* __restrict__ out) {
    const int row = blockIdx.x;
    const int tid = threadIdx.x;
    const float4 v = ((const float4*)(x + (size_t)row * 1024))[tid];
    float s = v.x + v.y + v.z + v.w;
    float q = v.x * v.x + v.y * v.y + v.z * v.z + v.w * v.w;
#pragma unroll
    for (int d = 1; d < 64; d <<= 1) {
        s += __shfl_xor(s, d, 64);
        q += __shfl_xor(q, d, 64);
    }
    __shared__ float ss[4], sq[4];
    const int wv = tid >> 6;
    if ((tid & 63) == 0) { ss[wv] = s; sq[wv] = q; }
    __syncthreads();
    s = ss[0] + ss[1] + ss[2] + ss[3];
    q = sq[0] + sq[1] + sq[2] + sq[3];
    const float mu = s * (1.0f / 1024.0f);
    const float var = q * (1.0f / 1024.0f) - mu * mu;
    const float rs = rsqrtf(var + 1e-5f);
    const int c = tid * 4;
    ushort4 o;
    o.x = f2bf((v.x - mu) * rs * g[c + 0] + bb[c + 0]);
    o.y = f2bf((v.y - mu) * rs * g[c + 1] + bb[c + 1]);
    o.z = f2bf((v.z - mu) * rs * g[c + 2] + bb[c + 2]);
    o.w = f2bf((v.w - mu) * rs * g[c + 3] + bb[c + 3]);
    *(ushort4*)&out[(size_t)row * 1024 + c] = o;
}

// ---------------- GEMM v6: small-block high-occupancy (unchanged from R9) ----
template <int MODE>
__global__ __launch_bounds__(256, 4) void gemms(const unsigned short* __restrict__ A,
                                                const unsigned short* __restrict__ Bw,
                                                void* __restrict__ Out,
                                                const float* __restrict__ bias,
                                                const float* __restrict__ res,
                                                int M, int N, int K, int gn) {
    __shared__ unsigned short lds[2 * 8192];  // [buf][A 128x32 | B 128x32]

    const int tid = threadIdx.x;
    const int l = tid & 63, w = tid >> 6;
    const int nwg = gridDim.x;
    const int sw = (blockIdx.x & 7) * (nwg >> 3) + (blockIdx.x >> 3);  // XCD swizzle
    const int m0 = (sw / gn) * 128;
    const int n0 = (sw % gn) * 128;
    const int wm = w >> 1, wn = w & 1;
    const int fr = l & 15, kg = l >> 4;
    const int sgq = ((l & 3) - ((l >> 3) & 3)) & 3;  // global slot (inverse rotation)
    const int srow = w * 16 + (l >> 2);              // per-lane staging row

    const unsigned short* gA0 = A + (size_t)(m0 + srow) * K + sgq * 8;
    const unsigned short* gA1 = gA0 + (size_t)64 * K;
    const unsigned short* gB0 = Bw + (size_t)(n0 + srow) * K + sgq * 8;
    const unsigned short* gB1 = gB0 + (size_t)64 * K;
    const int rowb = (w * 16) * 32;  // wave-uniform LDS dest base (ushorts)

    f32x4 acc[4][4] = {};

    auto stage = [&](int bufi, int k0) {
        unsigned short* base = lds + bufi * 8192;
        gload_lds16(gA0 + k0, base + rowb);
        gload_lds16(gA1 + k0, base + 2048 + rowb);
        gload_lds16(gB0 + k0, base + 4096 + rowb);
        gload_lds16(gB1 + k0, base + 6144 + rowb);
    };
    auto compute = [&](int bufi) {
        const unsigned short* As = lds + bufi * 8192;
        const unsigned short* Bs = As + 4096;
        bf16x8 af[4], bf[4];
#pragma unroll
        for (int i = 0; i < 4; ++i) {
            const int r = wm * 64 + i * 16 + fr;
            af[i] = *(const bf16x8*)&As[r * 32 + (((kg + ((r >> 1) & 3)) & 3) * 8)];
        }
#pragma unroll
        for (int j = 0; j < 4; ++j) {
            const int r = wn * 64 + j * 16 + fr;
            bf[j] = *(const bf16x8*)&Bs[r * 32 + (((kg + ((r >> 1) & 3)) & 3) * 8)];
        }
#pragma unroll
        for (int i = 0; i < 4; ++i)
#pragma unroll
            for (int j = 0; j < 4; ++j)
                acc[i][j] = __builtin_amdgcn_mfma_f32_16x16x32_bf16(bf[j], af[i], acc[i][j], 0, 0, 0);
    };

    const int NT = K >> 5;
    stage(0, 0);
    int cur = 0;
    for (int t = 0; t < NT; ++t) {
        if (t + 1 < NT) {
            stage(cur ^ 1, (t + 1) << 5);
            VMC(4);               // wait cur's 4 loads; keep next 4 in flight
        } else {
            VMC(0);
        }
        __builtin_amdgcn_s_barrier();
        __builtin_amdgcn_sched_barrier(0);
        compute(cur);
        __builtin_amdgcn_sched_barrier(0);
        __builtin_amdgcn_s_barrier();
        cur ^= 1;
    }

    const int cq = kg * 4;
#pragma unroll
    for (int mt = 0; mt < 4; ++mt) {
        const int row = m0 + wm * 64 + mt * 16 + fr;
#pragma unroll
        for (int nt = 0; nt < 4; ++nt) {
            const int col = n0 + wn * 64 + nt * 16 + cq;
            const f32x4 a = acc[mt][nt];
            if (MODE == 0) {
                ushort4 o;
                o.x = f2bf(a[0]); o.y = f2bf(a[1]); o.z = f2bf(a[2]); o.w = f2bf(a[3]);
                *(ushort4*)&((unsigned short*)Out)[(size_t)row * N + col] = o;
            } else if (MODE == 1) {
                const float4 bi = *(const float4*)&bias[col];
                const float4 re = *(const float4*)&res[(size_t)row * N + col];
                float4 o;
                o.x = a[0] + bi.x + re.x; o.y = a[1] + bi.y + re.y;
                o.z = a[2] + bi.z + re.z; o.w = a[3] + bi.w + re.w;
                *(float4*)&((float*)Out)[(size_t)row * N + col] = o;
            } else {
                const float4 bi = *(const float4*)&bias[col];
                ushort4 o;
                o.x = f2bf(gelu_exact(a[0] + bi.x));
                o.y = f2bf(gelu_exact(a[1] + bi.y));
                o.z = f2bf(gelu_exact(a[2] + bi.z));
                o.w = f2bf(gelu_exact(a[3] + bi.w));
                *(ushort4*)&((unsigned short*)Out)[(size_t)row * N + col] = o;
            }
        }
    }
}

// ---------------- Flash attention v3: double-buffered prefetch (T14) ----------
// Per KV tile t: issue K gload_lds(t+1) + V global->reg(t+1) BEFORE compute(t);
// after PV, vmcnt(0) (covered by ~compute) -> ds_write V(t+1) -> lgkmcnt(0) ->
// raw s_barrier (never __syncthreads: it would drain the prefetch).
// LDS: K 2x8KB + V 2x8KB + P 8KB = 40KB -> 4 blocks/CU.
__global__ __launch_bounds__(256) void attn_kernel(const unsigned short* __restrict__ qkv,
                                                   const int* __restrict__ length,
                                                   unsigned short* __restrict__ y) {
    const int id2 = (blockIdx.x & 7) * 256 + (blockIdx.x >> 3);
    const int qt = id2 & 15;
    const int h = (id2 >> 4) & 15;
    const int b = id2 >> 8;
    const int tid = threadIdx.x, lane = tid & 63, w = tid >> 6;
    const int q0 = qt * 64;
    const int len = length[b];
    const int ntiles = (len + 63) >> 6;

    __shared__ unsigned short Ks[2][64 * 64];   // [k][d] swizzled
    __shared__ unsigned short Vs[2][64 * 64];   // [d][k] swizzled (transposed)
    __shared__ unsigned short Ps[4 * 16 * 64];  // per-wave P, swizzled

    const int fr = lane & 15, kg = lane >> 4;

    bf16x8 qf[2];
    {
        const unsigned short* qb = qkv + (size_t)(b * Nn + q0 + w * 16 + fr) * 3072 + h * 64 + kg * 8;
        qf[0] = *(const bf16x8*)(qb);
        qf[1] = *(const bf16x8*)(qb + 32);
    }

    float m[4] = {-1e30f, -1e30f, -1e30f, -1e30f};
    float lsum[4] = {0.f, 0.f, 0.f, 0.f};
    f32x4 accO[4] = {};

    const int krow_l = lane >> 3;
    const int kslot = lane & 7;
    const int vk0 = (tid >> 3) * 2;          // thread's V row pair
    const int vd0 = (tid & 7) * 8;           // thread's V col block
    const unsigned short* vbase = qkv + (size_t)(b * Nn) * 3072 + 2048 + h * 64 + vd0;

    uint4 vr0, vr1;  // in-flight V registers (T14 async-split)

    auto stageK = [&](int kvt, int bufi) {
#pragma unroll
        for (int c = 0; c < 2; ++c) {
            const int k = c * 32 + w * 8 + krow_l;
            const int ss = kslot ^ ((k ^ (k >> 3)) & 7);
            gload_lds16(qkv + (size_t)(b * Nn + kvt + k) * 3072 + 1024 + h * 64 + ss * 8,
                        &Ks[bufi][(c * 32 + w * 8) * 64]);
        }
    };
    auto loadV = [&](int kvt) {
        vr0 = *(const uint4*)(vbase + (size_t)(kvt + vk0) * 3072);
        vr1 = *(const uint4*)(vbase + (size_t)(kvt + vk0 + 1) * 3072);
    };
    auto writeV = [&](int bufi) {
        const unsigned* a0 = (const unsigned*)&vr0;
        const unsigned* a1 = (const unsigned*)&vr1;
#pragma unroll
        for (int i = 0; i < 8; ++i) {
            const unsigned lo = (a0[i >> 1] >> ((i & 1) * 16)) & 0xffffu;
            const unsigned hi = (a1[i >> 1] >> ((i & 1) * 16)) & 0xffffu;
            const int d = vd0 + i;
            const int off = (d * 128 + vk0 * 2) ^ (((d ^ (d >> 3)) & 7) << 4);
            *(unsigned*)((char*)&Vs[bufi][0] + off) = lo | (hi << 16);
        }
    };

    // prologue: stage tile 0 into buffer 0
    stageK(0, 0);
    loadV(0);
    VMC(0);
    writeV(0);
    __syncthreads();

    for (int t = 0; t < ntiles; ++t) {
        const int kv0 = t << 6;
        const int cur = t & 1;
        const bool pre = (t + 1 < ntiles);
        if (pre) {                      // issue next tile's loads under this tile's compute
            stageK((t + 1) << 6, cur ^ 1);
            loadV((t + 1) << 6);
        }

        // --- QK^T from Ks[cur]
        f32x4 accS[4] = {};
        __builtin_amdgcn_s_setprio(1);
#pragma unroll
        for (int nt = 0; nt < 4; ++nt) {
            const int kr = nt * 16 + fr;
            const int swz = ((kr ^ (kr >> 3)) & 7) << 4;
#pragma unroll
            for (int kt = 0; kt < 2; ++kt) {
                bf16x8 kf = *(const bf16x8*)((const char*)&Ks[cur][0] +
                             ((kr * 128 + (kt * 32 + kg * 8) * 2) ^ swz));
                accS[nt] = __builtin_amdgcn_mfma_f32_16x16x32_bf16(qf[kt], kf, accS[nt], 0, 0, 0);
            }
        }
        __builtin_amdgcn_s_setprio(0);

        // --- online softmax (rows q = kg*4+r, reduce over fr lanes)
        const bool full = (kv0 + 64 <= len);   // wave-uniform: skip mask adds
        float p[4][4], sc[4];
#pragma unroll
        for (int r = 0; r < 4; ++r) {
            float sv[4];
            float mx = -1e30f;
#pragma unroll
            for (int nt = 0; nt < 4; ++nt) {
                sv[nt] = accS[nt][r] * SCALEf;
                if (!full) sv[nt] += (kv0 + nt * 16 + fr >= len) ? -10000.0f : 0.0f;
                mx = fmaxf(mx, sv[nt]);
            }
#pragma unroll
            for (int d = 1; d < 16; d <<= 1) mx = fmaxf(mx, __shfl_xor(mx, d, 64));
            const float mnew = fmaxf(m[r], mx);
            sc[r] = __expf(m[r] - mnew);
            float rsum = 0.f;
#pragma unroll
            for (int nt = 0; nt < 4; ++nt) {
                p[nt][r] = __expf(sv[nt] - mnew);
                rsum += p[nt][r];
            }
#pragma unroll
            for (int d = 1; d < 16; d <<= 1) rsum += __shfl_xor(rsum, d, 64);
            lsum[r] = lsum[r] * sc[r] + rsum;
            m[r] = mnew;
        }
#pragma unroll
        for (int nd = 0; nd < 4; ++nd)
#pragma unroll
            for (int r = 0; r < 4; ++r) accO[nd][r] *= sc[r];

        // --- P -> per-wave LDS (swizzled)
#pragma unroll
        for (int r = 0; r < 4; ++r) {
            const int q = kg * 4 + r;
            const int swz = ((q ^ (q >> 3)) & 7) << 4;
#pragma unroll
            for (int nt = 0; nt < 4; ++nt) {
                const int kk = nt * 16 + fr;
                *(unsigned short*)((char*)Ps + ((w * 2048 + q * 128 + kk * 2) ^ swz)) = f2bf(p[nt][r]);
            }
        }
        __builtin_amdgcn_wave_barrier();

        // --- PV from Vs[cur]
        const int swzp = ((fr ^ (fr >> 3)) & 7) << 4;
        __builtin_amdgcn_s_setprio(1);
#pragma unroll
        for (int kt = 0; kt < 2; ++kt) {
            bf16x8 pf = *(const bf16x8*)((const char*)Ps +
                        ((w * 2048 + fr * 128 + (kt * 32 + kg * 8) * 2) ^ swzp));
#pragma unroll
            for (int nd = 0; nd < 4; ++nd) {
                const int d = nd * 16 + fr;
                const int swzv = ((d ^ (d >> 3)) & 7) << 4;
                bf16x8 vf = *(const bf16x8*)((const char*)&Vs[cur][0] +
                            ((d * 128 + (kt * 32 + kg * 8) * 2) ^ swzv));
                accO[nd] = __builtin_amdgcn_mfma_f32_16x16x32_bf16(pf, vf, accO[nd], 0, 0, 0);
            }
        }
        __builtin_amdgcn_s_setprio(0);

        if (pre) {
            VMC(0);            // K(t+1) in LDS, V(t+1) in regs — covered by compute above
            writeV(cur ^ 1);   // transpose V(t+1) into the alternate buffer
        }
        LGKM0v;
        __builtin_amdgcn_s_barrier();
        __builtin_amdgcn_sched_barrier(0);
    }

#pragma unroll
    for (int r = 0; r < 4; ++r) {
        const float inv = 1.0f / lsum[r];
        const int row = q0 + w * 16 + kg * 4 + r;
#pragma unroll
        for (int nd = 0; nd < 4; ++nd)
            y[(size_t)(b * Nn + row) * 1024 + h * 64 + nd * 16 + fr] = f2bf(accO[nd][r] * inv);
    }
}

// ---------------- launch ----------------
extern "C" void kernel_launch(void* const* d_in, const int* in_sizes, int n_in,
                              void* d_out, int out_size, void* d_ws, size_t ws_size,
                              hipStream_t stream) {
    (void)in_sizes; (void)n_in; (void)out_size; (void)ws_size;
    const float* x     = (const float*)d_in[0];
    const int*   len   = (const int*)d_in[1];
    const float* g1    = (const float*)d_in[2];
    const float* b1    = (const float*)d_in[3];
    const float* Wqkv  = (const float*)d_in[4];
    const float* Wproj = (const float*)d_in[5];
    const float* bproj = (const float*)d_in[6];
    const float* g2    = (const float*)d_in[7];
    const float* b2    = (const float*)d_in[8];
    const float* W1    = (const float*)d_in[9];
    const float* bb1   = (const float*)d_in[10];
    const float* W2    = (const float*)d_in[11];
    const float* bb2   = (const float*)d_in[12];
    float* out = (float*)d_out;

    char* ws = (char*)d_ws;
    size_t off = 0;
    auto alloc = [&](size_t bytes) {
        void* p = ws + off;
        off += (bytes + 255) & ~(size_t)255;
        return p;
    };
    unsigned short* xn  = (unsigned short*)alloc(8192ULL * 1024 * 2);
    unsigned short* qkv = (unsigned short*)alloc(8192ULL * 3072 * 2);
    unsigned short* yb  = (unsigned short*)alloc(8192ULL * 1024 * 2);
    float* x2           = (float*)alloc(8192ULL * 1024 * 4);
    unsigned short* wqkv_b  = (unsigned short*)alloc(3072ULL * 1024 * 2);
    unsigned short* wproj_b = (unsigned short*)alloc(1024ULL * 1024 * 2);
    unsigned short* w1_b    = (unsigned short*)alloc(4096ULL * 1024 * 2);
    unsigned short* w2_b    = (unsigned short*)alloc(1024ULL * 4096 * 2);
    unsigned short* hb = qkv;  // reuse: qkv+yb dead by MLP1

    cvt_bf16<<<3072 * 1024 / 4 / 256, 256, 0, stream>>>(Wqkv, wqkv_b, 3072 * 1024 / 4);
    cvt_bf16<<<1024 * 1024 / 4 / 256, 256, 0, stream>>>(Wproj, wproj_b, 1024 * 1024 / 4);
    cvt_bf16<<<4096 * 1024 / 4 / 256, 256, 0, stream>>>(W1, w1_b, 4096 * 1024 / 4);
    cvt_bf16<<<4096 * 1024 / 4 / 256, 256, 0, stream>>>(W2, w2_b, 4096 * 1024 / 4);

    ln_kernel<<<8192, 256, 0, stream>>>(x, g1, b1, xn);
    gemms<0><<<1536, 256, 0, stream>>>(xn, wqkv_b, qkv, nullptr, nullptr, 8192, 3072, 1024, 24);
    attn_kernel<<<2048, 256, 0, stream>>>(qkv, len, yb);
    gemms<1><<<512, 256, 0, stream>>>(yb, wproj_b, x2, bproj, x, 8192, 1024, 1024, 8);
    ln_kernel<<<8192, 256, 0, stream>>>(x2, g2, b2, xn);
    gemms<2><<<2048, 256, 0, stream>>>(xn, w1_b, hb, bb1, nullptr, 8192, 4096, 1024, 32);
    gemms<1><<<512, 256, 0, stream>>>(hb, w2_b, out, bb2, x2, 8192, 1024, 4096, 8);
}

// Round 11
// 398.374 us; speedup vs baseline: 1.0673x; 1.0673x over previous
//
#include <hip/hip_runtime.h>
#include <math.h>

#define Bn 8
#define Nn 1024
#define Cn 1024
#define Hn 16
#define Dn 64
#define HIDn 4096
#define SCALEf 0.125f

typedef __bf16 bf16x8 __attribute__((ext_vector_type(8)));
typedef float f32x4 __attribute__((ext_vector_type(4)));

__device__ inline unsigned short f2bf(float f) {
    union { float f; unsigned int u; } v; v.f = f;
    unsigned int r = v.u + 0x7fffu + ((v.u >> 16) & 1u);
    return (unsigned short)(r >> 16);
}

// exact-GELU via inlined Abramowitz-Stegun erf (|err|<=1.5e-7). No libm call.
__device__ inline float gelu_exact(float x) {
    const float z = x * 0.70710678118654752f;
    const float az = fabsf(z);
    const float t = 1.0f / (1.0f + 0.3275911f * az);
    float poly = 0.254829592f +
                 t * (-0.284496736f +
                      t * (1.421413741f + t * (-1.453152027f + t * 1.061405429f)));
    poly *= t;
    const float e = __expf(-az * az);
    float erfv = 1.0f - poly * e;
    erfv = (z < 0.0f) ? -erfv : erfv;
    return 0.5f * x * (1.0f + erfv);
}

__device__ inline void gload_lds16(const void* g, void* l) {
    auto gp = reinterpret_cast<const unsigned int __attribute__((address_space(1)))*>(
        reinterpret_cast<uintptr_t>(g));
    auto lp = reinterpret_cast<unsigned int __attribute__((address_space(3)))*>(
        reinterpret_cast<uintptr_t>(l));
    __builtin_amdgcn_global_load_lds(gp, lp, 16, 0, 0);
}

#define VMC(n)                                           \
    asm volatile("s_waitcnt vmcnt(" #n ")" ::: "memory");\
    __builtin_amdgcn_sched_barrier(0)
#define LGKM0v                                           \
    asm volatile("s_waitcnt lgkmcnt(0)" ::: "memory");   \
    __builtin_amdgcn_sched_barrier(0)

// ---------------- f32 -> bf16 conversion ----------------
__global__ __launch_bounds__(256) void cvt_bf16(const float* __restrict__ in,
                                                unsigned short* __restrict__ out, int n4) {
    int i = blockIdx.x * 256 + threadIdx.x;
    if (i < n4) {
        float4 v = ((const float4*)in)[i];
        ushort4 o;
        o.x = f2bf(v.x); o.y = f2bf(v.y); o.z = f2bf(v.z); o.w = f2bf(v.w);
        ((ushort4*)out)[i] = o;
    }
}

// ---------------- LayerNorm (C=1024), fp32 in -> bf16 out ----------------
__global__ __launch_bounds__(256) void ln_kernel(const float* __restrict__ x,
                                                 const float* __restrict__ g,
                                                 const float* __restrict__ bb,
                                                 unsigned short* __restrict__ out) {
    const int row = blockIdx.x;
    const int tid = threadIdx.x;
    const float4 v = ((const float4*)(x + (size_t)row * 1024))[tid];
    float s = v.x + v.y + v.z + v.w;
    float q = v.x * v.x + v.y * v.y + v.z * v.z + v.w * v.w;
#pragma unroll
    for (int d = 1; d < 64; d <<= 1) {
        s += __shfl_xor(s, d, 64);
        q += __shfl_xor(q, d, 64);
    }
    __shared__ float ss[4], sq[4];
    const int wv = tid >> 6;
    if ((tid & 63) == 0) { ss[wv] = s; sq[wv] = q; }
    __syncthreads();
    s = ss[0] + ss[1] + ss[2] + ss[3];
    q = sq[0] + sq[1] + sq[2] + sq[3];
    const float mu = s * (1.0f / 1024.0f);
    const float var = q * (1.0f / 1024.0f) - mu * mu;
    const float rs = rsqrtf(var + 1e-5f);
    const int c = tid * 4;
    ushort4 o;
    o.x = f2bf((v.x - mu) * rs * g[c + 0] + bb[c + 0]);
    o.y = f2bf((v.y - mu) * rs * g[c + 1] + bb[c + 1]);
    o.z = f2bf((v.z - mu) * rs * g[c + 2] + bb[c + 2]);
    o.w = f2bf((v.w - mu) * rs * g[c + 3] + bb[c + 3]);
    *(ushort4*)&out[(size_t)row * 1024 + c] = o;
}

// ---------------- GEMM v6: small-block high-occupancy (unchanged from R9) ----
template <int MODE>
__global__ __launch_bounds__(256, 4) void gemms(const unsigned short* __restrict__ A,
                                                const unsigned short* __restrict__ Bw,
                                                void* __restrict__ Out,
                                                const float* __restrict__ bias,
                                                const float* __restrict__ res,
                                                int M, int N, int K, int gn) {
    __shared__ unsigned short lds[2 * 8192];  // [buf][A 128x32 | B 128x32]

    const int tid = threadIdx.x;
    const int l = tid & 63, w = tid >> 6;
    const int nwg = gridDim.x;
    const int sw = (blockIdx.x & 7) * (nwg >> 3) + (blockIdx.x >> 3);  // XCD swizzle
    const int m0 = (sw / gn) * 128;
    const int n0 = (sw % gn) * 128;
    const int wm = w >> 1, wn = w & 1;
    const int fr = l & 15, kg = l >> 4;
    const int sgq = ((l & 3) - ((l >> 3) & 3)) & 3;  // global slot (inverse rotation)
    const int srow = w * 16 + (l >> 2);              // per-lane staging row

    const unsigned short* gA0 = A + (size_t)(m0 + srow) * K + sgq * 8;
    const unsigned short* gA1 = gA0 + (size_t)64 * K;
    const unsigned short* gB0 = Bw + (size_t)(n0 + srow) * K + sgq * 8;
    const unsigned short* gB1 = gB0 + (size_t)64 * K;
    const int rowb = (w * 16) * 32;  // wave-uniform LDS dest base (ushorts)

    f32x4 acc[4][4] = {};

    auto stage = [&](int bufi, int k0) {
        unsigned short* base = lds + bufi * 8192;
        gload_lds16(gA0 + k0, base + rowb);
        gload_lds16(gA1 + k0, base + 2048 + rowb);
        gload_lds16(gB0 + k0, base + 4096 + rowb);
        gload_lds16(gB1 + k0, base + 6144 + rowb);
    };
    auto compute = [&](int bufi) {
        const unsigned short* As = lds + bufi * 8192;
        const unsigned short* Bs = As + 4096;
        bf16x8 af[4], bf[4];
#pragma unroll
        for (int i = 0; i < 4; ++i) {
            const int r = wm * 64 + i * 16 + fr;
            af[i] = *(const bf16x8*)&As[r * 32 + (((kg + ((r >> 1) & 3)) & 3) * 8)];
        }
#pragma unroll
        for (int j = 0; j < 4; ++j) {
            const int r = wn * 64 + j * 16 + fr;
            bf[j] = *(const bf16x8*)&Bs[r * 32 + (((kg + ((r >> 1) & 3)) & 3) * 8)];
        }
#pragma unroll
        for (int i = 0; i < 4; ++i)
#pragma unroll
            for (int j = 0; j < 4; ++j)
                acc[i][j] = __builtin_amdgcn_mfma_f32_16x16x32_bf16(bf[j], af[i], acc[i][j], 0, 0, 0);
    };

    const int NT = K >> 5;
    stage(0, 0);
    int cur = 0;
    for (int t = 0; t < NT; ++t) {
        if (t + 1 < NT) {
            stage(cur ^ 1, (t + 1) << 5);
            VMC(4);               // wait cur's 4 loads; keep next 4 in flight
        } else {
            VMC(0);
        }
        __builtin_amdgcn_s_barrier();
        __builtin_amdgcn_sched_barrier(0);
        compute(cur);
        __builtin_amdgcn_sched_barrier(0);
        __builtin_amdgcn_s_barrier();
        cur ^= 1;
    }

    const int cq = kg * 4;
#pragma unroll
    for (int mt = 0; mt < 4; ++mt) {
        const int row = m0 + wm * 64 + mt * 16 + fr;
#pragma unroll
        for (int nt = 0; nt < 4; ++nt) {
            const int col = n0 + wn * 64 + nt * 16 + cq;
            const f32x4 a = acc[mt][nt];
            if (MODE == 0) {
                ushort4 o;
                o.x = f2bf(a[0]); o.y = f2bf(a[1]); o.z = f2bf(a[2]); o.w = f2bf(a[3]);
                *(ushort4*)&((unsigned short*)Out)[(size_t)row * N + col] = o;
            } else if (MODE == 1) {
                const float4 bi = *(const float4*)&bias[col];
                const float4 re = *(const float4*)&res[(size_t)row * N + col];
                float4 o;
                o.x = a[0] + bi.x + re.x; o.y = a[1] + bi.y + re.y;
                o.z = a[2] + bi.z + re.z; o.w = a[3] + bi.w + re.w;
                *(float4*)&((float*)Out)[(size_t)row * N + col] = o;
            } else {
                const float4 bi = *(const float4*)&bias[col];
                ushort4 o;
                o.x = f2bf(gelu_exact(a[0] + bi.x));
                o.y = f2bf(gelu_exact(a[1] + bi.y));
                o.z = f2bf(gelu_exact(a[2] + bi.z));
                o.w = f2bf(gelu_exact(a[3] + bi.w));
                *(ushort4*)&((unsigned short*)Out)[(size_t)row * N + col] = o;
            }
        }
    }
}

// ---------------- Flash attention v4: swapped QK^T, lane-local softmax --------
// mfma(K,Q) puts S[kv][q=fr] lane-local: 16 kv-values/lane for ONE q-row.
// Row reduction = in-register tree + 2 shfl_xor (vs 32 serial shfl before).
// P-writes: 4x ds_write_b64 (vs 16x ds_write_u16). PV unchanged.
__global__ __launch_bounds__(256) void attn_kernel(const unsigned short* __restrict__ qkv,
                                                   const int* __restrict__ length,
                                                   unsigned short* __restrict__ y) {
    const int id2 = (blockIdx.x & 7) * 256 + (blockIdx.x >> 3);
    const int qt = id2 & 15;
    const int h = (id2 >> 4) & 15;
    const int b = id2 >> 8;
    const int tid = threadIdx.x, lane = tid & 63, w = tid >> 6;
    const int q0 = qt * 64;
    const int len = length[b];
    const int ntiles = (len + 63) >> 6;

    __shared__ unsigned short Ks[2][64 * 64];   // [k][d] swizzled
    __shared__ unsigned short Vs[2][64 * 64];   // [d][k] swizzled (transposed)
    __shared__ unsigned short Ps[4 * 16 * 64];  // per-wave P, swizzled

    const int fr = lane & 15, kg = lane >> 4;

    bf16x8 qf[2];
    {
        const unsigned short* qb = qkv + (size_t)(b * Nn + q0 + w * 16 + fr) * 3072 + h * 64 + kg * 8;
        qf[0] = *(const bf16x8*)(qb);
        qf[1] = *(const bf16x8*)(qb + 32);
    }

    float mrow = -1e30f;   // running max for q = q0 + w*16 + fr (this lane's row)
    float lrow = 0.f;      // running sum for that row
    f32x4 accO[4] = {};    // O[q=kg*4+r][d=nd*16+fr]

    const int krow_l = lane >> 3;
    const int kslot = lane & 7;
    const int vk0 = (tid >> 3) * 2;
    const int vd0 = (tid & 7) * 8;
    const unsigned short* vbase = qkv + (size_t)(b * Nn) * 3072 + 2048 + h * 64 + vd0;

    uint4 vr0, vr1;

    auto stageK = [&](int kvt, int bufi) {
#pragma unroll
        for (int c = 0; c < 2; ++c) {
            const int k = c * 32 + w * 8 + krow_l;
            const int ss = kslot ^ ((k ^ (k >> 3)) & 7);
            gload_lds16(qkv + (size_t)(b * Nn + kvt + k) * 3072 + 1024 + h * 64 + ss * 8,
                        &Ks[bufi][(c * 32 + w * 8) * 64]);
        }
    };
    auto loadV = [&](int kvt) {
        vr0 = *(const uint4*)(vbase + (size_t)(kvt + vk0) * 3072);
        vr1 = *(const uint4*)(vbase + (size_t)(kvt + vk0 + 1) * 3072);
    };
    auto writeV = [&](int bufi) {
        const unsigned* a0 = (const unsigned*)&vr0;
        const unsigned* a1 = (const unsigned*)&vr1;
#pragma unroll
        for (int i = 0; i < 8; ++i) {
            const unsigned lo = (a0[i >> 1] >> ((i & 1) * 16)) & 0xffffu;
            const unsigned hi = (a1[i >> 1] >> ((i & 1) * 16)) & 0xffffu;
            const int d = vd0 + i;
            const int off = (d * 128 + vk0 * 2) ^ (((d ^ (d >> 3)) & 7) << 4);
            *(unsigned*)((char*)&Vs[bufi][0] + off) = lo | (hi << 16);
        }
    };

    stageK(0, 0);
    loadV(0);
    VMC(0);
    writeV(0);
    __syncthreads();

    const int swzp = ((fr ^ (fr >> 3)) & 7) << 4;

    for (int t = 0; t < ntiles; ++t) {
        const int kv0 = t << 6;
        const int cur = t & 1;
        const bool pre = (t + 1 < ntiles);
        if (pre) {
            stageK((t + 1) << 6, cur ^ 1);
            loadV((t + 1) << 6);
        }

        // --- swapped QK^T: accT[nt][r] = S[kv = nt*16+kg*4+r][q = fr]
        f32x4 accT[4] = {};
        __builtin_amdgcn_s_setprio(1);
#pragma unroll
        for (int nt = 0; nt < 4; ++nt) {
            const int kr = nt * 16 + fr;
            const int swz = ((kr ^ (kr >> 3)) & 7) << 4;
#pragma unroll
            for (int kt = 0; kt < 2; ++kt) {
                bf16x8 kf = *(const bf16x8*)((const char*)&Ks[cur][0] +
                             ((kr * 128 + (kt * 32 + kg * 8) * 2) ^ swz));
                accT[nt] = __builtin_amdgcn_mfma_f32_16x16x32_bf16(kf, qf[kt], accT[nt], 0, 0, 0);
            }
        }
        __builtin_amdgcn_s_setprio(0);

        // --- lane-local softmax (one q-row per lane)
        const bool full = (kv0 + 64 <= len);
        float sv[16];
        float mx = -1e30f;
#pragma unroll
        for (int nt = 0; nt < 4; ++nt)
#pragma unroll
            for (int r = 0; r < 4; ++r) {
                float s = accT[nt][r] * SCALEf;
                if (!full) s += (kv0 + nt * 16 + kg * 4 + r >= len) ? -10000.0f : 0.0f;
                sv[nt * 4 + r] = s;
            }
        // in-register max tree (8 + 4 + 2 + 1)
#pragma unroll
        for (int i = 0; i < 8; ++i) sv[i] = fmaxf(sv[i], sv[i + 8]), mx = mx;  // keep sv intact? no:
        // NOTE: need sv preserved for exp; do tree on copies
        {
            float t0[8];
#pragma unroll
            for (int i = 0; i < 8; ++i) t0[i] = fmaxf(sv[i], sv[i + 8]);
#pragma unroll
            for (int i = 0; i < 4; ++i) t0[i] = fmaxf(t0[i], t0[i + 4]);
            mx = fmaxf(fmaxf(t0[0], t0[1]), fmaxf(t0[2], t0[3]));
        }
        mx = fmaxf(mx, __shfl_xor(mx, 16, 64));
        mx = fmaxf(mx, __shfl_xor(mx, 32, 64));
        const float mnew = fmaxf(mrow, mx);
        const float scq = __expf(mrow - mnew);
        mrow = mnew;
        float p[16];
        float rsum = 0.f;
#pragma unroll
        for (int i = 0; i < 16; ++i) {
            p[i] = __expf(sv[i] - mnew);
            rsum += p[i];
        }
        rsum += __shfl_xor(rsum, 16, 64);
        rsum += __shfl_xor(rsum, 32, 64);
        lrow = lrow * scq + rsum;

        // broadcast rescale factor into accO's row layout (q = kg*4+r)
        float scr[4];
#pragma unroll
        for (int r = 0; r < 4; ++r) scr[r] = __shfl(scq, kg * 4 + r, 64);
#pragma unroll
        for (int nd = 0; nd < 4; ++nd)
#pragma unroll
            for (int r = 0; r < 4; ++r) accO[nd][r] *= scr[r];

        // --- P -> per-wave LDS: 4x ds_write_b64 (kv consecutive per nt)
#pragma unroll
        for (int nt = 0; nt < 4; ++nt) {
            const unsigned lo = (unsigned)f2bf(p[nt * 4 + 0]) | ((unsigned)f2bf(p[nt * 4 + 1]) << 16);
            const unsigned hi = (unsigned)f2bf(p[nt * 4 + 2]) | ((unsigned)f2bf(p[nt * 4 + 3]) << 16);
            const int off = (w * 2048 + fr * 128 + nt * 32 + kg * 8) ^ swzp;
            uint2 pk; pk.x = lo; pk.y = hi;
            *(uint2*)((char*)Ps + off) = pk;
        }
        __builtin_amdgcn_wave_barrier();

        // --- PV from Vs[cur]
        __builtin_amdgcn_s_setprio(1);
#pragma unroll
        for (int kt = 0; kt < 2; ++kt) {
            bf16x8 pf = *(const bf16x8*)((const char*)Ps +
                        ((w * 2048 + fr * 128 + (kt * 32 + kg * 8) * 2) ^ swzp));
#pragma unroll
            for (int nd = 0; nd < 4; ++nd) {
                const int d = nd * 16 + fr;
                const int swzv = ((d ^ (d >> 3)) & 7) << 4;
                bf16x8 vf = *(const bf16x8*)((const char*)&Vs[cur][0] +
                            ((d * 128 + (kt * 32 + kg * 8) * 2) ^ swzv));
                accO[nd] = __builtin_amdgcn_mfma_f32_16x16x32_bf16(pf, vf, accO[nd], 0, 0, 0);
            }
        }
        __builtin_amdgcn_s_setprio(0);

        if (pre) {
            VMC(0);
            writeV(cur ^ 1);
        }
        LGKM0v;
        __builtin_amdgcn_s_barrier();
        __builtin_amdgcn_sched_barrier(0);
    }

    // epilogue: fetch each accO-row's lsum from its owner lane
    float lr[4];
#pragma unroll
    for (int r = 0; r < 4; ++r) lr[r] = __shfl(lrow, kg * 4 + r, 64);
#pragma unroll
    for (int r = 0; r < 4; ++r) {
        const float inv = 1.0f / lr[r];
        const int row = q0 + w * 16 + kg * 4 + r;
#pragma unroll
        for (int nd = 0; nd < 4; ++nd)
            y[(size_t)(b * Nn + row) * 1024 + h * 64 + nd * 16 + fr] = f2bf(accO[nd][r] * inv);
    }
}

// ---------------- launch ----------------
extern "C" void kernel_launch(void* const* d_in, const int* in_sizes, int n_in,
                              void* d_out, int out_size, void* d_ws, size_t ws_size,
                              hipStream_t stream) {
    (void)in_sizes; (void)n_in; (void)out_size; (void)ws_size;
    const float* x     = (const float*)d_in[0];
    const int*   len   = (const int*)d_in[1];
    const float* g1    = (const float*)d_in[2];
    const float* b1    = (const float*)d_in[3];
    const float* Wqkv  = (const float*)d_in[4];
    const float* Wproj = (const float*)d_in[5];
    const float* bproj = (const float*)d_in[6];
    const float* g2    = (const float*)d_in[7];
    const float* b2    = (const float*)d_in[8];
    const float* W1    = (const float*)d_in[9];
    const float* bb1   = (const float*)d_in[10];
    const float* W2    = (const float*)d_in[11];
    const float* bb2   = (const float*)d_in[12];
    float* out = (float*)d_out;

    char* ws = (char*)d_ws;
    size_t off = 0;
    auto alloc = [&](size_t bytes) {
        void* p = ws + off;
        off += (bytes + 255) & ~(size_t)255;
        return p;
    };
    unsigned short* xn  = (unsigned short*)alloc(8192ULL * 1024 * 2);
    unsigned short* qkv = (unsigned short*)alloc(8192ULL * 3072 * 2);
    unsigned short* yb  = (unsigned short*)alloc(8192ULL * 1024 * 2);
    float* x2           = (float*)alloc(8192ULL * 1024 * 4);
    unsigned short* wqkv_b  = (unsigned short*)alloc(3072ULL * 1024 * 2);
    unsigned short* wproj_b = (unsigned short*)alloc(1024ULL * 1024 * 2);
    unsigned short* w1_b    = (unsigned short*)alloc(4096ULL * 1024 * 2);
    unsigned short* w2_b    = (unsigned short*)alloc(1024ULL * 4096 * 2);
    unsigned short* hb = qkv;  // reuse: qkv+yb dead by MLP1

    cvt_bf16<<<3072 * 1024 / 4 / 256, 256, 0, stream>>>(Wqkv, wqkv_b, 3072 * 1024 / 4);
    cvt_bf16<<<1024 * 1024 / 4 / 256, 256, 0, stream>>>(Wproj, wproj_b, 1024 * 1024 / 4);
    cvt_bf16<<<4096 * 1024 / 4 / 256, 256, 0, stream>>>(W1, w1_b, 4096 * 1024 / 4);
    cvt_bf16<<<4096 * 1024 / 4 / 256, 256, 0, stream>>>(W2, w2_b, 4096 * 1024 / 4);

    ln_kernel<<<8192, 256, 0, stream>>>(x, g1, b1, xn);
    gemms<0><<<1536, 256, 0, stream>>>(xn, wqkv_b, qkv, nullptr, nullptr, 8192, 3072, 1024, 24);
    attn_kernel<<<2048, 256, 0, stream>>>(qkv, len, yb);
    gemms<1><<<512, 256, 0, stream>>>(yb, wproj_b, x2, bproj, x, 8192, 1024, 1024, 8);
    ln_kernel<<<8192, 256, 0, stream>>>(x2, g2, b2, xn);
    gemms<2><<<2048, 256, 0, stream>>>(xn, w1_b, hb, bb1, nullptr, 8192, 4096, 1024, 32);
    gemms<1><<<512, 256, 0, stream>>>(hb, w2_b, out, bb2, x2, 8192, 1024, 4096, 8);
}